// Round 2
// baseline (178.342 us; speedup 1.0000x reference)
//
#include <hip/hip_runtime.h>

// PWLU channelwise, fixed bounds. x: [32,256,56,56] f32, points: [256,7] f32.
// Uniform-grid identity (branchless, no gathers):
//   xn = (x + 2.7)/0.9
//   out = p[0] + sum_j d_j * t_j,  d_j = p[j+1]-p[j]
//     t_0 = min(xn, 1)            (unclamped below -> linear extrapolation)
//     t_j = clamp(xn - j, 0, 1)   j = 1..4
//     t_5 = max(xn - 5, 0)        (unclamped above -> linear extrapolation)
// Matches reference piecewise-linear values exactly (continuous at knots).
//
// 8 elems/thread (2x float4). 3136 elems/plane = 392 chunks/plane, so each
// 8-elem chunk is channel-uniform. 3,211,264 chunks = 12,544 blocks x 256.

typedef float f4 __attribute__((ext_vector_type(4)));

#define CHUNKS_PER_PLANE 392
#define N_PTS 7

__global__ __launch_bounds__(256) void pwlu_kernel(
    const float* __restrict__ x,
    const float* __restrict__ points,
    float* __restrict__ out,
    int nchunk) {
  int i = blockIdx.x * blockDim.x + threadIdx.x;
  if (i >= nchunk) return;

  // channel of this chunk (uniform across the 8 elems)
  int c = (i / CHUNKS_PER_PLANE) & 255;
  const float* __restrict__ p = points + c * N_PTS;
  float p0 = p[0];
  float d0 = p[1] - p0;
  float d1 = p[2] - p[1];
  float d2 = p[3] - p[2];
  float d3 = p[4] - p[3];
  float d4 = p[5] - p[4];
  float d5 = p[6] - p[5];

  const f4* __restrict__ xv = reinterpret_cast<const f4*>(x) + (size_t)i * 2;
  f4 a = __builtin_nontemporal_load(xv);
  f4 b = __builtin_nontemporal_load(xv + 1);

  float v[8] = {a.x, a.y, a.z, a.w, b.x, b.y, b.z, b.w};
  float r_[8];
#pragma unroll
  for (int k = 0; k < 8; ++k) {
    // xn = x/0.9 + 3.0  (2.7/0.9 == 3 exactly in fp32)
    float xn = fmaf(v[k], 1.0f / 0.9f, 3.0f);
    float acc = fmaf(d0, fminf(xn, 1.0f), p0);
    acc = fmaf(d1, fminf(fmaxf(xn - 1.0f, 0.0f), 1.0f), acc);  // v_med3
    acc = fmaf(d2, fminf(fmaxf(xn - 2.0f, 0.0f), 1.0f), acc);
    acc = fmaf(d3, fminf(fmaxf(xn - 3.0f, 0.0f), 1.0f), acc);
    acc = fmaf(d4, fminf(fmaxf(xn - 4.0f, 0.0f), 1.0f), acc);
    acc = fmaf(d5, fmaxf(xn - 5.0f, 0.0f), acc);
    r_[k] = acc;
  }

  f4 oa = {r_[0], r_[1], r_[2], r_[3]};
  f4 ob = {r_[4], r_[5], r_[6], r_[7]};
  f4* __restrict__ ov = reinterpret_cast<f4*>(out) + (size_t)i * 2;
  __builtin_nontemporal_store(oa, ov);
  __builtin_nontemporal_store(ob, ov + 1);
}

extern "C" void kernel_launch(void* const* d_in, const int* in_sizes, int n_in,
                              void* d_out, int out_size, void* d_ws, size_t ws_size,
                              hipStream_t stream) {
  const float* x      = (const float*)d_in[0];
  const float* points = (const float*)d_in[1];
  float* out          = (float*)d_out;

  int n = in_sizes[0];          // 25,690,112
  int nchunk = n / 8;           // 3,211,264 = 12,544 * 256
  int threads = 256;
  int blocks = (nchunk + threads - 1) / threads;
  pwlu_kernel<<<blocks, threads, 0, stream>>>(x, points, out, nchunk);
}